// Round 10
// baseline (243.737 us; speedup 1.0000x reference)
//
#include <hip/hip_runtime.h>
#include <math.h>

// Conv2dSelfAttention MI355X — round 10: attn_core with m=32 quad-buffer and
// counted-vmcnt schedule (T3/T4): stage 2 chunks ahead, vmcnt(3) at barriers.
// B=16, C=512, N=4096, M=1024, CB=64, CG=256.

typedef unsigned short u16;
typedef short bf16x8 __attribute__((ext_vector_type(8)));
typedef float f32x16 __attribute__((ext_vector_type(16)));
typedef u16 u16x4 __attribute__((ext_vector_type(4)));
typedef int i32x4 __attribute__((ext_vector_type(4)));

#define MFMA32 __builtin_amdgcn_mfma_f32_32x32x16_bf16
#define B_ 16
#define C_ 512
#define N_ 4096
#define M_ 1024
#define LOG2E 1.44269504088896f
#define FIXMAX 8.0f

__device__ __forceinline__ u16 f2b(float f) {  // fp32 -> bf16 RNE
  unsigned u = __float_as_uint(f);
  return (u16)((u + 0x7FFFu + ((u >> 16) & 1u)) >> 16);
}
__device__ __forceinline__ unsigned cvtpk(float a, float b) {  // lo=a, hi=b
  unsigned r;
  asm("v_cvt_pk_bf16_f32 %0, %1, %2" : "=v"(r) : "v"(a), "v"(b));
  return r;
}
__device__ __forceinline__ void permswap(unsigned &a, unsigned &b) {
  asm("v_permlane32_swap_b32 %0, %1" : "+v"(a), "+v"(b));
}
__device__ __forceinline__ float exp2v(float a) {
  float r;
  asm("v_exp_f32 %0, %1" : "=v"(r) : "v"(a));
  return r;
}
__device__ __forceinline__ void async_cp16(u16* lds, const u16* g) {
  __builtin_amdgcn_global_load_lds(
      (const __attribute__((address_space(1))) unsigned int*)g,
      (__attribute__((address_space(3))) unsigned int*)lds, 16, 0, 0);
}
__device__ __forceinline__ f32x16 fz16() {
  f32x16 z;
#pragma unroll
  for (int i = 0; i < 16; ++i) z[i] = 0.0f;
  return z;
}

// Fragment-linear layouts (lane l = hi*32+lo, e = 0..7):
//  weights [O][512]: fW(o,c) = (((o>>5)*8 + (c>>6))*4 + ((c>>4)&3))*512
//                              + (((c>>3)&1)*32 + (o&31))*8 + (c&7)
//  wo [512][256]:  fWO(c,k) = ((c>>5)*16 + (k>>4))*512 + (((k>>3)&1)*32 + (c&31))*8 + (k&7)
//  th [b][n][cb]:  (jq*4+kh)*512 + l*8 + e            (jq = n>>5)
//  ph [b][m][cb]:  (jm*4+kh)*512 + l*8 + e            (jm = m>>5)
//  vt [b][cg][m]:  ((ic*8+ct)*4+kh)*512 + l*8 + e     (ic=m>>6, ct=cg>>5, kh=(m>>4)&3)
//  O  [b][q][cg]:  (jq*16+f)*512 + l*8 + e            (f = cg>>4) — B-frag linear

// ---------------- weights fp32 -> bf16, tiled ----------------
__global__ __launch_bounds__(256) void cvt_all_kernel(
    const float* __restrict__ w_theta, const float* __restrict__ w_phi,
    const float* __restrict__ w_g, const float* __restrict__ w_out,
    const float* __restrict__ gamma, u16* __restrict__ dth, u16* __restrict__ dph,
    u16* __restrict__ dg, u16* __restrict__ dwo) {
  int i = blockIdx.x * 256 + threadIdx.x;
  if (i < 16384) {  // wth / wph : 64 x 512
    const float* s = (i < 8192) ? w_theta : w_phi;
    u16* d = (i < 8192) ? dth : dph;
    float scale = (i < 8192) ? LOG2E : 1.0f;
    int j = i & 8191;
    int o = j >> 7, c = (j & 127) * 4;
    float4 vv = *(const float4*)(s + (size_t)o * 512 + c);
    int idx = (((o >> 5) * 8 + (c >> 6)) * 4 + ((c >> 4) & 3)) * 512 +
              (((c >> 3) & 1) * 32 + (o & 31)) * 8 + (c & 7);
    u16x4 ot = {f2b(vv.x * scale), f2b(vv.y * scale), f2b(vv.z * scale), f2b(vv.w * scale)};
    *(u16x4*)(d + idx) = ot;
  } else if (i < 49152) {  // wg : 256 x 512
    int j = i - 16384;
    int o = j >> 7, c = (j & 127) * 4;
    float4 vv = *(const float4*)(w_g + (size_t)o * 512 + c);
    int idx = (((o >> 5) * 8 + (c >> 6)) * 4 + ((c >> 4) & 3)) * 512 +
              (((c >> 3) & 1) * 32 + (o & 31)) * 8 + (c & 7);
    u16x4 ot = {f2b(vv.x), f2b(vv.y), f2b(vv.z), f2b(vv.w)};
    *(u16x4*)(dg + idx) = ot;
  } else {  // wo : 512 x 256, gamma-prescaled
    int j = i - 49152;
    int o = j >> 6, k = (j & 63) * 4;
    float scale = gamma[0];
    float4 vv = *(const float4*)(w_out + (size_t)o * 256 + k);
    int idx = ((o >> 5) * 16 + (k >> 4)) * 512 +
              (((k >> 3) & 1) * 32 + (o & 31)) * 8 + (k & 7);
    u16x4 ot = {f2b(vv.x * scale), f2b(vv.y * scale), f2b(vv.z * scale), f2b(vv.w * scale)};
    *(u16x4*)(dwo + idx) = ot;
  }
}

// ---------------- fused prep: transpose + pool + theta/phi/g convs ----------------
// grid (32 nb, 16 b), 512 thr (8 waves). waves 0-3: theta; waves 4-7: g (+phi on 4,5).
__global__ __launch_bounds__(512) void prep_kernel(
    const float* __restrict__ x, const u16* __restrict__ wth,
    const u16* __restrict__ wph, const u16* __restrict__ wg,
    const float* __restrict__ bth, const float* __restrict__ bph,
    const float* __restrict__ bg, u16* __restrict__ th, u16* __restrict__ ph,
    u16* __restrict__ vt) {
  __shared__ u16 xb[128 * 68];   // [n][c-local], c-blocks XOR-swizzled
  __shared__ u16 xpt[32 * 68];   // [m][c-local]
  const int t = threadIdx.x;
  const int w = t >> 6, l = t & 63, lo = l & 31, hi = l >> 5;
  const int nb = blockIdx.x, b = blockIdx.y;
  const int n0 = nb * 128;
  const int lcol = (t & 31) * 4;  // n within 128
  const int lrow = t >> 5;        // c-row 0..15 (rows lrow+16i)

  f32x16 acc0 = fz16(), acc1 = fz16(), a_ph = fz16();

  float v[16];
  auto loadv = [&](int c0) {
#pragma unroll
    for (int i = 0; i < 4; ++i) {
      float4 f = *(const float4*)(x + ((size_t)(b * C_ + c0 + lrow + 16 * i)) * N_ + n0 + lcol);
      v[4*i] = f.x; v[4*i+1] = f.y; v[4*i+2] = f.z; v[4*i+3] = f.w;
    }
  };
  auto writeT = [&]() {
#pragma unroll
    for (int i = 0; i < 4; ++i) {
      int c = lrow + 16 * i;
      int blk = c >> 3;
#pragma unroll
      for (int k = 0; k < 4; ++k) {
        int n = lcol + k;
        int swz = ((n >> 2) ^ (n >> 5)) & 7;
        xb[n * 68 + ((blk ^ swz) * 8) + (c & 7)] = f2b(v[4*i+k]);
      }
    }
    float pA[4], pB[4];
#pragma unroll
    for (int i = 0; i < 4; ++i) {
      pA[i] = v[4*i] + v[4*i+1];
      pB[i] = v[4*i+2] + v[4*i+3];
    }
#pragma unroll
    for (int i = 0; i < 4; ++i) {
      pA[i] += __shfl_xor(pA[i], 16, 64);
      pB[i] += __shfl_xor(pB[i], 16, 64);
    }
    if ((t & 31) < 16) {
      int m0 = (t & 31) * 2;
#pragma unroll
      for (int i = 0; i < 4; ++i) {
        int c = lrow + 16 * i;
        xpt[m0 * 68 + c] = f2b(0.25f * pA[i]);
        xpt[(m0 + 1) * 68 + c] = f2b(0.25f * pB[i]);
      }
    }
  };
  auto domfma = [&](int c0b) {
    if (w < 4) {  // theta: A = xb rows 32w+lo
      const int n = 32 * w + lo;
      const int rbase = n * 68;
      const int nswz = ((n >> 2) ^ (n >> 5)) & 7;
#pragma unroll
      for (int kh = 0; kh < 4; ++kh) {
        bf16x8 xa = *(const bf16x8*)(&xb[rbase + (((2*kh + hi) ^ nswz) * 8)]);
        bf16x8 w0 = *(const bf16x8*)(wth + ((c0b) * 4 + kh) * 512 + l * 8);
        bf16x8 w1 = *(const bf16x8*)(wth + ((8 + c0b) * 4 + kh) * 512 + l * 8);
        acc0 = MFMA32(xa, w0, acc0, 0, 0, 0);
        acc1 = MFMA32(xa, w1, acc1, 0, 0, 0);
      }
    } else {  // g (+phi): B = xpt rows m=lo
      const int wg4 = w - 4;
      const u16* xpw = &xpt[lo * 68];
#pragma unroll
      for (int kh = 0; kh < 4; ++kh) {
        bf16x8 xp8 = *(const bf16x8*)(xpw + kh * 16 + hi * 8);
        bf16x8 g0 = *(const bf16x8*)(wg + ((16*wg4 + c0b) * 4 + kh) * 512 + l * 8);
        bf16x8 g1 = *(const bf16x8*)(wg + ((16*wg4 + 8 + c0b) * 4 + kh) * 512 + l * 8);
        acc0 = MFMA32(g0, xp8, acc0, 0, 0, 0);
        acc1 = MFMA32(g1, xp8, acc1, 0, 0, 0);
        if (wg4 < 2) {
          bf16x8 wp8 = *(const bf16x8*)(wph + ((wg4*8 + c0b) * 4 + kh) * 512 + l * 8);
          a_ph = MFMA32(xp8, wp8, a_ph, 0, 0, 0);
        }
      }
    }
  };

  loadv(0);
  for (int i = 0; i < 8; ++i) {
    if (i) __syncthreads();
    writeT();
    if (i < 7) loadv((i + 1) * 64);
    __syncthreads();
    domfma(i);
  }

  int rr[16];
#pragma unroll
  for (int r = 0; r < 16; ++r) rr[r] = (r & 3) + 8 * (r >> 2) + 4 * hi;

  if (w < 4) {  // th (tiled)
    u16* thb = th + (size_t)b * 262144;
#pragma unroll
    for (int r = 0; r < 16; ++r) {
      int sub = (((lo >> 3) & 1) * 32 + rr[r]) * 8 + (lo & 7);
      thb[((nb*4 + w)*4 + (lo >> 4)) * 512 + sub]     = f2b(acc0[r] + LOG2E * bth[lo]);
      thb[((nb*4 + w)*4 + 2 + (lo >> 4)) * 512 + sub] = f2b(acc1[r] + LOG2E * bth[32 + lo]);
    }
  } else {
    const int wg4 = w - 4;
    u16* vtb = vt + (size_t)b * 262144;
#pragma unroll
    for (int r = 0; r < 16; ++r) {  // vt (tiled)
      int cg0 = 64 * wg4 + rr[r];
      int sub = (((lo >> 3) & 1) * 32 + rr[r]) * 8 + (lo & 7);
      int kk = (nb & 1) * 2 + (lo >> 4);
      vtb[(((nb >> 1) * 8 + 2*wg4) * 4 + kk) * 512 + sub]     = f2b(acc0[r] + bg[cg0]);
      vtb[(((nb >> 1) * 8 + 2*wg4 + 1) * 4 + kk) * 512 + sub] = f2b(acc1[r] + bg[cg0 + 32]);
    }
    if (wg4 < 2) {  // ph (tiled)
      u16* phb = ph + (size_t)b * 65536;
#pragma unroll
      for (int r = 0; r < 16; ++r) {
        int sub = (((lo >> 3) & 1) * 32 + rr[r]) * 8 + (lo & 7);
        phb[(nb*4 + 2*wg4 + (lo >> 4)) * 512 + sub] = f2b(a_ph[r] + bph[32*wg4 + lo]);
      }
    }
  }
}

// ---------------- attention core: flash loop -> normalized O (tiled) ----------------
// grid (32,16) XCD-swizzled; 512 thr = 4 q-pairs x 2 cg-halves; 128 q/block.
// m-chunks of 32; 4 LDS buffers of 20KB (V 16KB + phi 4KB); stage 2 chunks
// ahead; vmcnt(3) at barriers keeps one stage in flight (counted-wait, T3/T4).
__global__ __launch_bounds__(512, 4) void attn_core_kernel(
    const u16* __restrict__ th, const u16* __restrict__ ph,
    const u16* __restrict__ vt, u16* __restrict__ Og) {
  __shared__ u16 smem[40960];  // 80KB: 4 bufs x { V 8192 u16 | phi 2048 u16 }

  const int t = threadIdx.x;
  const int w = t >> 6, l = t & 63;
  const int p = w & 3, h = w >> 2;
  const int flat = blockIdx.y * 32 + blockIdx.x;
  const int nf = (flat & 7) * 64 + (flat >> 3);  // bijective XCD swizzle
  const int b = nf >> 5, nb5 = nf & 31;
  const int jqt = nb5 * 4 + p;  // 32q-tile index in batch

  const u16* thb = th + (size_t)b * 262144;
  const u16* phb = ph + (size_t)b * 65536;
  const u16* vtb = vt + (size_t)b * 262144;

  bf16x8 thB[4];
#pragma unroll
  for (int kh = 0; kh < 4; ++kh)
    thB[kh] = *(const bf16x8*)(thb + (jqt * 4 + kh) * 512 + l * 8);

  f32x16 acc[4];
#pragma unroll
  for (int ct = 0; ct < 4; ++ct) acc[ct] = fz16();
  float sp[4] = {0.0f, 0.0f, 0.0f, 0.0f};

  // stage m-chunk k (k = ic*2+jml) into buffer k&3: 3 loads per thread.
  auto stage = [&](int k) {
    const int ic = k >> 1, jml = k & 1;
    u16* base = &smem[(k & 3) * 10240];
#pragma unroll
    for (int i = 0; i < 2; ++i) {  // V 16KB
      int o = t * 8 + i * 4096;
      const u16* src = vtb + (size_t)(ic * 32 + (o >> 10) * 4 + 2 * jml) * 512 + (o & 1023);
      async_cp16(base + o, src);
    }
    {  // phi 4KB (wave-halves duplicate: same bytes, benign)
      int o = (t & 255) * 8;
      const u16* src = phb + (size_t)((2 * ic + jml) * 4) * 512 + o;
      async_cp16(base + 8192 + o, src);
    }
  };

  stage(0);
  stage(1);
  asm volatile("s_waitcnt vmcnt(3)" ::: "memory");  // chunk 0 landed; 1 in flight
  __builtin_amdgcn_sched_barrier(0);
  __builtin_amdgcn_s_barrier();

#pragma unroll 4
  for (int k = 0; k < 32; ++k) {
    if (k < 30) stage(k + 2);

    const u16* Vs = &smem[(k & 3) * 10240];
    const u16* Ps = Vs + 8192;

    // QK^T swapped: S^T (q = lane lo, m-local over regs); phi from LDS
    f32x16 S = fz16();
#pragma unroll
    for (int kh = 0; kh < 4; ++kh) {
      bf16x8 pf = *(const bf16x8*)(Ps + kh * 512 + l * 8);
      S = MFMA32(pf, thB[kh], S, 0, 0, 0);
    }

    // P = exp2(S - FIXMAX) (exact pow2, cancels in normalize); deferred sum
#pragma unroll
    for (int i = 0; i < 16; ++i) {
      S[i] = exp2v(S[i] - FIXMAX);
      sp[i & 3] += S[i];
    }

    // P -> bf16 B-frags (cvt_pk + permlane32_swap)
    bf16x8 Pf[2];
#pragma unroll
    for (int s = 0; s < 2; ++s) {
      unsigned a0 = cvtpk(S[8*s+0], S[8*s+1]);
      unsigned a1 = cvtpk(S[8*s+2], S[8*s+3]);
      unsigned a2 = cvtpk(S[8*s+4], S[8*s+5]);
      unsigned a3 = cvtpk(S[8*s+6], S[8*s+7]);
      permswap(a0, a2);
      permswap(a1, a3);
      i32x4 wv = {(int)a0, (int)a1, (int)a2, (int)a3};
      Pf[s] = __builtin_bit_cast(bf16x8, wv);
    }

    // PV (transposed): acc[ct2] += V^T-frag (A, cg rows) @ Pf (B, col=q)
    __builtin_amdgcn_s_setprio(1);
#pragma unroll
    for (int ct2 = 0; ct2 < 4; ++ct2) {
      const u16* vp = Vs + (size_t)((4 * h + ct2) * 2) * 512 + l * 8;
      bf16x8 vf0 = *(const bf16x8*)(vp);
      bf16x8 vf1 = *(const bf16x8*)(vp + 512);
      acc[ct2] = MFMA32(vf0, Pf[0], acc[ct2], 0, 0, 0);
      acc[ct2] = MFMA32(vf1, Pf[1], acc[ct2], 0, 0, 0);
    }
    __builtin_amdgcn_s_setprio(0);

    // counted wait: drain stage(k+1); stage(k+2) stays in flight across barrier
    if (k < 30) {
      asm volatile("s_waitcnt vmcnt(3)" ::: "memory");
      __builtin_amdgcn_sched_barrier(0);
      __builtin_amdgcn_s_barrier();
    } else if (k == 30) {
      asm volatile("s_waitcnt vmcnt(0)" ::: "memory");
      __builtin_amdgcn_sched_barrier(0);
      __builtin_amdgcn_s_barrier();
    }
  }

  float lsum = (sp[0] + sp[1]) + (sp[2] + sp[3]);
  lsum += __shfl_xor(lsum, 32, 64);
  const float linv = 1.0f / lsum;

  // normalize + pack O -> global (frag-linear: (jqt*16+f)*512 + l*8)
  u16* Ob = Og + (size_t)b * 1048576 + (size_t)jqt * 16 * 512;
#pragma unroll
  for (int ct2 = 0; ct2 < 4; ++ct2) {
    f32x16& A = acc[ct2];
#pragma unroll
    for (int s = 0; s < 2; ++s) {
      unsigned a0 = cvtpk(A[8*s+0]*linv, A[8*s+1]*linv);
      unsigned a1 = cvtpk(A[8*s+2]*linv, A[8*s+3]*linv);
      unsigned a2 = cvtpk(A[8*s+4]*linv, A[8*s+5]*linv);
      unsigned a3 = cvtpk(A[8*s+6]*linv, A[8*s+7]*linv);
      permswap(a0, a2);
      permswap(a1, a3);
      i32x4 wv = {(int)a0, (int)a1, (int)a2, (int)a3};
      int f = 8 * h + 2 * ct2 + s;
      *(bf16x8*)(Ob + f * 512 + l * 8) = __builtin_bit_cast(bf16x8, wv);
    }
  }
}

// ---------------- streaming out-conv + residual ----------------
// grid (32,16) XCD-swizzled (same mapping as core => O L2-local); 512 thr,
// wave (p,h): q-tile p (32 q), c-half h. No LDS, no barriers.
__global__ __launch_bounds__(512, 4) void outconv_kernel(
    const u16* __restrict__ Og, const u16* __restrict__ wo,
    const float* __restrict__ b_out, const float* __restrict__ gamma,
    const float* __restrict__ x, float* __restrict__ out) {
  const int t = threadIdx.x;
  const int w = t >> 6, l = t & 63, lo = l & 31, hi = l >> 5;
  const int p = w & 3, h = w >> 2;
  const int flat = blockIdx.y * 32 + blockIdx.x;
  const int nf = (flat & 7) * 64 + (flat >> 3);
  const int b = nf >> 5, nb5 = nf & 31;
  const int jqt = nb5 * 4 + p;
  const int qp = jqt * 32;

  // O B-frags (k=cg 0..255, col=q)
  const u16* Ob = Og + (size_t)b * 1048576 + (size_t)jqt * 16 * 512;
  bf16x8 Of[16];
#pragma unroll
  for (int f = 0; f < 16; ++f)
    Of[f] = *(const bf16x8*)(Ob + f * 512 + l * 8);

  int rr[16];
#pragma unroll
  for (int r = 0; r < 16; ++r) rr[r] = (r & 3) + 8 * (r >> 2) + 4 * hi;

  const float gamma0 = gamma[0];
  for (int ctc = 0; ctc < 8; ++ctc) {
    f32x16 facc = fz16();
    const u16* wp = wo + (size_t)((8 * h + ctc) * 16) * 512 + l * 8;
#pragma unroll
    for (int f = 0; f < 16; ++f) {
      bf16x8 wfr = *(const bf16x8*)(wp + f * 512);
      facc = MFMA32(wfr, Of[f], facc, 0, 0, 0);  // wo gamma-prescaled
    }
#pragma unroll
    for (int r = 0; r < 16; ++r) {
      int c = 256 * h + 32 * ctc + rr[r];
      size_t idx = ((size_t)(b * C_ + c)) * N_ + qp + lo;
      float xv = __builtin_nontemporal_load(&x[idx]);
      __builtin_nontemporal_store(facc[r] + gamma0 * b_out[c] + xv, &out[idx]);
    }
  }
}

extern "C" void kernel_launch(void* const* d_in, const int* in_sizes, int n_in,
                              void* d_out, int out_size, void* d_ws, size_t ws_size,
                              hipStream_t stream) {
  (void)in_sizes; (void)n_in; (void)out_size; (void)ws_size;
  const float* x       = (const float*)d_in[0];
  const float* w_theta = (const float*)d_in[1];
  const float* b_theta = (const float*)d_in[2];
  const float* w_phi   = (const float*)d_in[3];
  const float* b_phi   = (const float*)d_in[4];
  const float* w_g     = (const float*)d_in[5];
  const float* b_g     = (const float*)d_in[6];
  const float* w_out   = (const float*)d_in[7];
  const float* b_out   = (const float*)d_in[8];
  const float* gamma   = (const float*)d_in[9];
  float* out = (float*)d_out;

  char* ws = (char*)d_ws;
  u16* th  = (u16*)(ws);               // 16*262144*2 = 8,388,608
  u16* ph  = (u16*)(ws + 8388608);     // 16*65536*2  = 2,097,152
  u16* vt  = (u16*)(ws + 10485760);    // 16*262144*2 = 8,388,608
  u16* wth = (u16*)(ws + 18874368);    // 65,536
  u16* wph = (u16*)(ws + 18939904);    // 65,536
  u16* wg  = (u16*)(ws + 19005440);    // 262,144
  u16* wo  = (u16*)(ws + 19267584);    // 262,144 (end 19,529,728)
  u16* Og  = (u16*)(ws + 19529728);    // 16*1048576*2 = 33,554,432 (end 53,084,160)

  cvt_all_kernel<<<320, 256, 0, stream>>>(w_theta, w_phi, w_g, w_out, gamma,
                                          wth, wph, wg, wo);
  prep_kernel<<<dim3(32, 16), 512, 0, stream>>>(x, wth, wph, wg, b_theta, b_phi,
                                                b_g, th, ph, vt);
  attn_core_kernel<<<dim3(32, 16), 512, 0, stream>>>(th, ph, vt, Og);
  outconv_kernel<<<dim3(32, 16), 512, 0, stream>>>(Og, wo, b_out, gamma, x, out);
}

// Round 11
// 181.805 us; speedup vs baseline: 1.3407x; 1.3407x over previous
//
#include <hip/hip_runtime.h>
#include <math.h>

// Conv2dSelfAttention MI355X — round 11: r9 structure, phi from L2 (V-only LDS).
// Cuts LDS-read pool 30.7->20.5 us/CU; register footprint unchanged.
// B=16, C=512, N=4096, M=1024, CB=64, CG=256.

typedef unsigned short u16;
typedef short bf16x8 __attribute__((ext_vector_type(8)));
typedef float f32x16 __attribute__((ext_vector_type(16)));
typedef u16 u16x4 __attribute__((ext_vector_type(4)));
typedef int i32x4 __attribute__((ext_vector_type(4)));

#define MFMA32 __builtin_amdgcn_mfma_f32_32x32x16_bf16
#define B_ 16
#define C_ 512
#define N_ 4096
#define M_ 1024
#define LOG2E 1.44269504088896f
#define FIXMAX 8.0f

__device__ __forceinline__ u16 f2b(float f) {  // fp32 -> bf16 RNE
  unsigned u = __float_as_uint(f);
  return (u16)((u + 0x7FFFu + ((u >> 16) & 1u)) >> 16);
}
__device__ __forceinline__ unsigned cvtpk(float a, float b) {  // lo=a, hi=b
  unsigned r;
  asm("v_cvt_pk_bf16_f32 %0, %1, %2" : "=v"(r) : "v"(a), "v"(b));
  return r;
}
__device__ __forceinline__ void permswap(unsigned &a, unsigned &b) {
  asm("v_permlane32_swap_b32 %0, %1" : "+v"(a), "+v"(b));
}
__device__ __forceinline__ float exp2v(float a) {
  float r;
  asm("v_exp_f32 %0, %1" : "=v"(r) : "v"(a));
  return r;
}
__device__ __forceinline__ void async_cp16(u16* lds, const u16* g) {
  __builtin_amdgcn_global_load_lds(
      (const __attribute__((address_space(1))) unsigned int*)g,
      (__attribute__((address_space(3))) unsigned int*)lds, 16, 0, 0);
}
__device__ __forceinline__ f32x16 fz16() {
  f32x16 z;
#pragma unroll
  for (int i = 0; i < 16; ++i) z[i] = 0.0f;
  return z;
}

// Fragment-linear layouts (lane l = hi*32+lo, e = 0..7):
//  weights [O][512]: fW(o,c) = (((o>>5)*8 + (c>>6))*4 + ((c>>4)&3))*512
//                              + (((c>>3)&1)*32 + (o&31))*8 + (c&7)
//  wo [512][256]:  fWO(c,k) = ((c>>5)*16 + (k>>4))*512 + (((k>>3)&1)*32 + (c&31))*8 + (k&7)
//  th [b][n][cb]:  (jq*4+kh)*512 + l*8 + e            (jq = n>>5)
//  ph [b][m][cb]:  (jm*4+kh)*512 + l*8 + e            (jm = m>>5)
//  vt [b][cg][m]:  ((ic*8+ct)*4+kh)*512 + l*8 + e     (ic=m>>6, ct=cg>>5, kh=(m>>4)&3)
//  O  [b][q][cg]:  (jq*16+f)*512 + l*8 + e            (f = cg>>4) — B-frag linear

// ---------------- weights fp32 -> bf16, tiled ----------------
__global__ __launch_bounds__(256) void cvt_all_kernel(
    const float* __restrict__ w_theta, const float* __restrict__ w_phi,
    const float* __restrict__ w_g, const float* __restrict__ w_out,
    const float* __restrict__ gamma, u16* __restrict__ dth, u16* __restrict__ dph,
    u16* __restrict__ dg, u16* __restrict__ dwo) {
  int i = blockIdx.x * 256 + threadIdx.x;
  if (i < 16384) {  // wth / wph : 64 x 512
    const float* s = (i < 8192) ? w_theta : w_phi;
    u16* d = (i < 8192) ? dth : dph;
    float scale = (i < 8192) ? LOG2E : 1.0f;
    int j = i & 8191;
    int o = j >> 7, c = (j & 127) * 4;
    float4 vv = *(const float4*)(s + (size_t)o * 512 + c);
    int idx = (((o >> 5) * 8 + (c >> 6)) * 4 + ((c >> 4) & 3)) * 512 +
              (((c >> 3) & 1) * 32 + (o & 31)) * 8 + (c & 7);
    u16x4 ot = {f2b(vv.x * scale), f2b(vv.y * scale), f2b(vv.z * scale), f2b(vv.w * scale)};
    *(u16x4*)(d + idx) = ot;
  } else if (i < 49152) {  // wg : 256 x 512
    int j = i - 16384;
    int o = j >> 7, c = (j & 127) * 4;
    float4 vv = *(const float4*)(w_g + (size_t)o * 512 + c);
    int idx = (((o >> 5) * 8 + (c >> 6)) * 4 + ((c >> 4) & 3)) * 512 +
              (((c >> 3) & 1) * 32 + (o & 31)) * 8 + (c & 7);
    u16x4 ot = {f2b(vv.x), f2b(vv.y), f2b(vv.z), f2b(vv.w)};
    *(u16x4*)(dg + idx) = ot;
  } else {  // wo : 512 x 256, gamma-prescaled
    int j = i - 49152;
    int o = j >> 6, k = (j & 63) * 4;
    float scale = gamma[0];
    float4 vv = *(const float4*)(w_out + (size_t)o * 256 + k);
    int idx = ((o >> 5) * 16 + (k >> 4)) * 512 +
              (((k >> 3) & 1) * 32 + (o & 31)) * 8 + (k & 7);
    u16x4 ot = {f2b(vv.x * scale), f2b(vv.y * scale), f2b(vv.z * scale), f2b(vv.w * scale)};
    *(u16x4*)(dwo + idx) = ot;
  }
}

// ---------------- fused prep: transpose + pool + theta/phi/g convs ----------------
// grid (32 nb, 16 b), 512 thr (8 waves). waves 0-3: theta; waves 4-7: g (+phi on 4,5).
__global__ __launch_bounds__(512) void prep_kernel(
    const float* __restrict__ x, const u16* __restrict__ wth,
    const u16* __restrict__ wph, const u16* __restrict__ wg,
    const float* __restrict__ bth, const float* __restrict__ bph,
    const float* __restrict__ bg, u16* __restrict__ th, u16* __restrict__ ph,
    u16* __restrict__ vt) {
  __shared__ u16 xb[128 * 68];   // [n][c-local], c-blocks XOR-swizzled
  __shared__ u16 xpt[32 * 68];   // [m][c-local]
  const int t = threadIdx.x;
  const int w = t >> 6, l = t & 63, lo = l & 31, hi = l >> 5;
  const int nb = blockIdx.x, b = blockIdx.y;
  const int n0 = nb * 128;
  const int lcol = (t & 31) * 4;  // n within 128
  const int lrow = t >> 5;        // c-row 0..15 (rows lrow+16i)

  f32x16 acc0 = fz16(), acc1 = fz16(), a_ph = fz16();

  float v[16];
  auto loadv = [&](int c0) {
#pragma unroll
    for (int i = 0; i < 4; ++i) {
      float4 f = *(const float4*)(x + ((size_t)(b * C_ + c0 + lrow + 16 * i)) * N_ + n0 + lcol);
      v[4*i] = f.x; v[4*i+1] = f.y; v[4*i+2] = f.z; v[4*i+3] = f.w;
    }
  };
  auto writeT = [&]() {
#pragma unroll
    for (int i = 0; i < 4; ++i) {
      int c = lrow + 16 * i;
      int blk = c >> 3;
#pragma unroll
      for (int k = 0; k < 4; ++k) {
        int n = lcol + k;
        int swz = ((n >> 2) ^ (n >> 5)) & 7;
        xb[n * 68 + ((blk ^ swz) * 8) + (c & 7)] = f2b(v[4*i+k]);
      }
    }
    float pA[4], pB[4];
#pragma unroll
    for (int i = 0; i < 4; ++i) {
      pA[i] = v[4*i] + v[4*i+1];
      pB[i] = v[4*i+2] + v[4*i+3];
    }
#pragma unroll
    for (int i = 0; i < 4; ++i) {
      pA[i] += __shfl_xor(pA[i], 16, 64);
      pB[i] += __shfl_xor(pB[i], 16, 64);
    }
    if ((t & 31) < 16) {
      int m0 = (t & 31) * 2;
#pragma unroll
      for (int i = 0; i < 4; ++i) {
        int c = lrow + 16 * i;
        xpt[m0 * 68 + c] = f2b(0.25f * pA[i]);
        xpt[(m0 + 1) * 68 + c] = f2b(0.25f * pB[i]);
      }
    }
  };
  auto domfma = [&](int c0b) {
    if (w < 4) {  // theta: A = xb rows 32w+lo
      const int n = 32 * w + lo;
      const int rbase = n * 68;
      const int nswz = ((n >> 2) ^ (n >> 5)) & 7;
#pragma unroll
      for (int kh = 0; kh < 4; ++kh) {
        bf16x8 xa = *(const bf16x8*)(&xb[rbase + (((2*kh + hi) ^ nswz) * 8)]);
        bf16x8 w0 = *(const bf16x8*)(wth + ((c0b) * 4 + kh) * 512 + l * 8);
        bf16x8 w1 = *(const bf16x8*)(wth + ((8 + c0b) * 4 + kh) * 512 + l * 8);
        acc0 = MFMA32(xa, w0, acc0, 0, 0, 0);
        acc1 = MFMA32(xa, w1, acc1, 0, 0, 0);
      }
    } else {  // g (+phi): B = xpt rows m=lo
      const int wg4 = w - 4;
      const u16* xpw = &xpt[lo * 68];
#pragma unroll
      for (int kh = 0; kh < 4; ++kh) {
        bf16x8 xp8 = *(const bf16x8*)(xpw + kh * 16 + hi * 8);
        bf16x8 g0 = *(const bf16x8*)(wg + ((16*wg4 + c0b) * 4 + kh) * 512 + l * 8);
        bf16x8 g1 = *(const bf16x8*)(wg + ((16*wg4 + 8 + c0b) * 4 + kh) * 512 + l * 8);
        acc0 = MFMA32(g0, xp8, acc0, 0, 0, 0);
        acc1 = MFMA32(g1, xp8, acc1, 0, 0, 0);
        if (wg4 < 2) {
          bf16x8 wp8 = *(const bf16x8*)(wph + ((wg4*8 + c0b) * 4 + kh) * 512 + l * 8);
          a_ph = MFMA32(xp8, wp8, a_ph, 0, 0, 0);
        }
      }
    }
  };

  loadv(0);
  for (int i = 0; i < 8; ++i) {
    if (i) __syncthreads();
    writeT();
    if (i < 7) loadv((i + 1) * 64);
    __syncthreads();
    domfma(i);
  }

  int rr[16];
#pragma unroll
  for (int r = 0; r < 16; ++r) rr[r] = (r & 3) + 8 * (r >> 2) + 4 * hi;

  if (w < 4) {  // th (tiled)
    u16* thb = th + (size_t)b * 262144;
#pragma unroll
    for (int r = 0; r < 16; ++r) {
      int sub = (((lo >> 3) & 1) * 32 + rr[r]) * 8 + (lo & 7);
      thb[((nb*4 + w)*4 + (lo >> 4)) * 512 + sub]     = f2b(acc0[r] + LOG2E * bth[lo]);
      thb[((nb*4 + w)*4 + 2 + (lo >> 4)) * 512 + sub] = f2b(acc1[r] + LOG2E * bth[32 + lo]);
    }
  } else {
    const int wg4 = w - 4;
    u16* vtb = vt + (size_t)b * 262144;
#pragma unroll
    for (int r = 0; r < 16; ++r) {  // vt (tiled)
      int cg0 = 64 * wg4 + rr[r];
      int sub = (((lo >> 3) & 1) * 32 + rr[r]) * 8 + (lo & 7);
      int kk = (nb & 1) * 2 + (lo >> 4);
      vtb[(((nb >> 1) * 8 + 2*wg4) * 4 + kk) * 512 + sub]     = f2b(acc0[r] + bg[cg0]);
      vtb[(((nb >> 1) * 8 + 2*wg4 + 1) * 4 + kk) * 512 + sub] = f2b(acc1[r] + bg[cg0 + 32]);
    }
    if (wg4 < 2) {  // ph (tiled)
      u16* phb = ph + (size_t)b * 65536;
#pragma unroll
      for (int r = 0; r < 16; ++r) {
        int sub = (((lo >> 3) & 1) * 32 + rr[r]) * 8 + (lo & 7);
        phb[(nb*4 + 2*wg4 + (lo >> 4)) * 512 + sub] = f2b(a_ph[r] + bph[32*wg4 + lo]);
      }
    }
  }
}

// ---------------- attention core: flash loop -> normalized O (tiled) ----------------
// grid (32,16) XCD-swizzled; 512 thr = 4 q-pairs x 2 cg-halves; 128 q/block.
// m-chunks of 64; V-only LDS double buffer (4 global_load_lds/wave/chunk);
// phi fragments read directly from global (L2-resident, 128KB/batch).
__global__ __launch_bounds__(512, 4) void attn_core_kernel(
    const u16* __restrict__ th, const u16* __restrict__ ph,
    const u16* __restrict__ vt, u16* __restrict__ Og) {
  __shared__ u16 smem[32768];  // 64KB: dbuf x V 16384 u16

  const int t = threadIdx.x;
  const int w = t >> 6, l = t & 63;
  const int p = w & 3, h = w >> 2;
  const int flat = blockIdx.y * 32 + blockIdx.x;
  const int nf = (flat & 7) * 64 + (flat >> 3);  // bijective XCD swizzle
  const int b = nf >> 5, nb5 = nf & 31;
  const int jqt = nb5 * 4 + p;  // 32q-tile index in batch

  const u16* thb = th + (size_t)b * 262144;
  const u16* phb = ph + (size_t)b * 65536;
  const u16* vtb = vt + (size_t)b * 262144;

  bf16x8 thB[4];
#pragma unroll
  for (int kh = 0; kh < 4; ++kh)
    thB[kh] = *(const bf16x8*)(thb + (jqt * 4 + kh) * 512 + l * 8);

  f32x16 acc[4];
#pragma unroll
  for (int ct = 0; ct < 4; ++ct) acc[ct] = fz16();
  float sp[4] = {0.0f, 0.0f, 0.0f, 0.0f};

  // stage V chunk ic into buffer nbuf: 32KB, 4 instrs/wave (linear dest+src).
  auto stage = [&](int nbuf, int ic) {
#pragma unroll
    for (int i = 0; i < 4; ++i) {
      int o = t * 8 + i * 4096;  // = (w*512 + l*8) + i*4096 : wave-uniform + lane*16B
      async_cp16(&smem[nbuf * 16384 + o], vtb + (size_t)ic * 16384 + o);
    }
  };

  stage(0, 0);
  asm volatile("s_waitcnt vmcnt(0)" ::: "memory");
  __builtin_amdgcn_sched_barrier(0);
  __builtin_amdgcn_s_barrier();

  int buf = 0;
  for (int ic = 0; ic < 16; ++ic) {
    if (ic < 15) stage(buf ^ 1, ic + 1);

    const u16* Vs = &smem[buf * 16384];
#pragma unroll
    for (int jml = 0; jml < 2; ++jml) {
      // QK^T swapped: S^T (q = lane lo, m-local over regs); phi from global/L2
      bf16x8 pf[4];
#pragma unroll
      for (int kh = 0; kh < 4; ++kh)
        pf[kh] = *(const bf16x8*)(phb + (size_t)((ic * 2 + jml) * 4 + kh) * 512 + l * 8);
      f32x16 S = fz16();
#pragma unroll
      for (int kh = 0; kh < 4; ++kh) S = MFMA32(pf[kh], thB[kh], S, 0, 0, 0);

      // P = exp2(S - FIXMAX) (exact pow2, cancels in normalize); deferred sum
#pragma unroll
      for (int i = 0; i < 16; ++i) {
        S[i] = exp2v(S[i] - FIXMAX);
        sp[i & 3] += S[i];
      }

      // P -> bf16 B-frags (cvt_pk + permlane32_swap)
      bf16x8 Pf[2];
#pragma unroll
      for (int s = 0; s < 2; ++s) {
        unsigned a0 = cvtpk(S[8*s+0], S[8*s+1]);
        unsigned a1 = cvtpk(S[8*s+2], S[8*s+3]);
        unsigned a2 = cvtpk(S[8*s+4], S[8*s+5]);
        unsigned a3 = cvtpk(S[8*s+6], S[8*s+7]);
        permswap(a0, a2);
        permswap(a1, a3);
        i32x4 wv = {(int)a0, (int)a1, (int)a2, (int)a3};
        Pf[s] = __builtin_bit_cast(bf16x8, wv);
      }

      // PV (transposed): acc[ct2] += V^T-frag (A, cg rows) @ Pf (B, col=q)
      __builtin_amdgcn_s_setprio(1);
#pragma unroll
      for (int ct2 = 0; ct2 < 4; ++ct2) {
        const u16* vp = Vs + ((4 * h + ct2) * 4 + jml * 2) * 512 + l * 8;
        bf16x8 vf0 = *(const bf16x8*)(vp);
        bf16x8 vf1 = *(const bf16x8*)(vp + 512);
        acc[ct2] = MFMA32(vf0, Pf[0], acc[ct2], 0, 0, 0);
        acc[ct2] = MFMA32(vf1, Pf[1], acc[ct2], 0, 0, 0);
      }
      __builtin_amdgcn_s_setprio(0);
    }

    if (ic < 15) {  // drain this wave's stage loads, then sync buffers
      asm volatile("s_waitcnt vmcnt(0)" ::: "memory");
      __builtin_amdgcn_sched_barrier(0);
      __builtin_amdgcn_s_barrier();
      buf ^= 1;
    }
  }

  float lsum = (sp[0] + sp[1]) + (sp[2] + sp[3]);
  lsum += __shfl_xor(lsum, 32, 64);
  const float linv = 1.0f / lsum;

  // normalize + pack O -> global (frag-linear: (jqt*16+f)*512 + l*8)
  u16* Ob = Og + (size_t)b * 1048576 + (size_t)jqt * 16 * 512;
#pragma unroll
  for (int ct2 = 0; ct2 < 4; ++ct2) {
    f32x16& A = acc[ct2];
#pragma unroll
    for (int s = 0; s < 2; ++s) {
      unsigned a0 = cvtpk(A[8*s+0]*linv, A[8*s+1]*linv);
      unsigned a1 = cvtpk(A[8*s+2]*linv, A[8*s+3]*linv);
      unsigned a2 = cvtpk(A[8*s+4]*linv, A[8*s+5]*linv);
      unsigned a3 = cvtpk(A[8*s+6]*linv, A[8*s+7]*linv);
      permswap(a0, a2);
      permswap(a1, a3);
      i32x4 wv = {(int)a0, (int)a1, (int)a2, (int)a3};
      int f = 8 * h + 2 * ct2 + s;
      *(bf16x8*)(Ob + f * 512 + l * 8) = __builtin_bit_cast(bf16x8, wv);
    }
  }
}

// ---------------- streaming out-conv + residual ----------------
// grid (32,16) XCD-swizzled (same mapping as core => O L2-local); 512 thr,
// wave (p,h): q-tile p (32 q), c-half h. No LDS, no barriers.
__global__ __launch_bounds__(512, 4) void outconv_kernel(
    const u16* __restrict__ Og, const u16* __restrict__ wo,
    const float* __restrict__ b_out, const float* __restrict__ gamma,
    const float* __restrict__ x, float* __restrict__ out) {
  const int t = threadIdx.x;
  const int w = t >> 6, l = t & 63, lo = l & 31, hi = l >> 5;
  const int p = w & 3, h = w >> 2;
  const int flat = blockIdx.y * 32 + blockIdx.x;
  const int nf = (flat & 7) * 64 + (flat >> 3);
  const int b = nf >> 5, nb5 = nf & 31;
  const int jqt = nb5 * 4 + p;
  const int qp = jqt * 32;

  // O B-frags (k=cg 0..255, col=q)
  const u16* Ob = Og + (size_t)b * 1048576 + (size_t)jqt * 16 * 512;
  bf16x8 Of[16];
#pragma unroll
  for (int f = 0; f < 16; ++f)
    Of[f] = *(const bf16x8*)(Ob + f * 512 + l * 8);

  int rr[16];
#pragma unroll
  for (int r = 0; r < 16; ++r) rr[r] = (r & 3) + 8 * (r >> 2) + 4 * hi;

  const float gamma0 = gamma[0];
  for (int ctc = 0; ctc < 8; ++ctc) {
    f32x16 facc = fz16();
    const u16* wp = wo + (size_t)((8 * h + ctc) * 16) * 512 + l * 8;
#pragma unroll
    for (int f = 0; f < 16; ++f) {
      bf16x8 wfr = *(const bf16x8*)(wp + f * 512);
      facc = MFMA32(wfr, Of[f], facc, 0, 0, 0);  // wo gamma-prescaled
    }
#pragma unroll
    for (int r = 0; r < 16; ++r) {
      int c = 256 * h + 32 * ctc + rr[r];
      size_t idx = ((size_t)(b * C_ + c)) * N_ + qp + lo;
      float xv = __builtin_nontemporal_load(&x[idx]);
      __builtin_nontemporal_store(facc[r] + gamma0 * b_out[c] + xv, &out[idx]);
    }
  }
}

extern "C" void kernel_launch(void* const* d_in, const int* in_sizes, int n_in,
                              void* d_out, int out_size, void* d_ws, size_t ws_size,
                              hipStream_t stream) {
  (void)in_sizes; (void)n_in; (void)out_size; (void)ws_size;
  const float* x       = (const float*)d_in[0];
  const float* w_theta = (const float*)d_in[1];
  const float* b_theta = (const float*)d_in[2];
  const float* w_phi   = (const float*)d_in[3];
  const float* b_phi   = (const float*)d_in[4];
  const float* w_g     = (const float*)d_in[5];
  const float* b_g     = (const float*)d_in[6];
  const float* w_out   = (const float*)d_in[7];
  const float* b_out   = (const float*)d_in[8];
  const float* gamma   = (const float*)d_in[9];
  float* out = (float*)d_out;

  char* ws = (char*)d_ws;
  u16* th  = (u16*)(ws);               // 16*262144*2 = 8,388,608
  u16* ph  = (u16*)(ws + 8388608);     // 16*65536*2  = 2,097,152
  u16* vt  = (u16*)(ws + 10485760);    // 16*262144*2 = 8,388,608
  u16* wth = (u16*)(ws + 18874368);    // 65,536
  u16* wph = (u16*)(ws + 18939904);    // 65,536
  u16* wg  = (u16*)(ws + 19005440);    // 262,144
  u16* wo  = (u16*)(ws + 19267584);    // 262,144 (end 19,529,728)
  u16* Og  = (u16*)(ws + 19529728);    // 16*1048576*2 = 33,554,432 (end 53,084,160)

  cvt_all_kernel<<<320, 256, 0, stream>>>(w_theta, w_phi, w_g, w_out, gamma,
                                          wth, wph, wg, wo);
  prep_kernel<<<dim3(32, 16), 512, 0, stream>>>(x, wth, wph, wg, b_theta, b_phi,
                                                b_g, th, ph, vt);
  attn_core_kernel<<<dim3(32, 16), 512, 0, stream>>>(th, ph, vt, Og);
  outconv_kernel<<<dim3(32, 16), 512, 0, stream>>>(Og, wo, b_out, gamma, x, out);
}

// Round 12
// 167.811 us; speedup vs baseline: 1.4524x; 1.0834x over previous
//
#include <hip/hip_runtime.h>
#include <math.h>

// Conv2dSelfAttention MI355X — round 12: counted-vmcnt quad-buffer, spill-safe.
// m-chunks of 32; 4 x 20KB LDS bufs (V+phi); stage 2 ahead; vmcnt(3) at
// barriers (one stage always in flight); no loop unroll; r9 register body.
// B=16, C=512, N=4096, M=1024, CB=64, CG=256.

typedef unsigned short u16;
typedef short bf16x8 __attribute__((ext_vector_type(8)));
typedef float f32x16 __attribute__((ext_vector_type(16)));
typedef u16 u16x4 __attribute__((ext_vector_type(4)));
typedef int i32x4 __attribute__((ext_vector_type(4)));

#define MFMA32 __builtin_amdgcn_mfma_f32_32x32x16_bf16
#define B_ 16
#define C_ 512
#define N_ 4096
#define M_ 1024
#define LOG2E 1.44269504088896f
#define FIXMAX 8.0f

__device__ __forceinline__ u16 f2b(float f) {  // fp32 -> bf16 RNE
  unsigned u = __float_as_uint(f);
  return (u16)((u + 0x7FFFu + ((u >> 16) & 1u)) >> 16);
}
__device__ __forceinline__ unsigned cvtpk(float a, float b) {  // lo=a, hi=b
  unsigned r;
  asm("v_cvt_pk_bf16_f32 %0, %1, %2" : "=v"(r) : "v"(a), "v"(b));
  return r;
}
__device__ __forceinline__ void permswap(unsigned &a, unsigned &b) {
  asm("v_permlane32_swap_b32 %0, %1" : "+v"(a), "+v"(b));
}
__device__ __forceinline__ float exp2v(float a) {
  float r;
  asm("v_exp_f32 %0, %1" : "=v"(r) : "v"(a));
  return r;
}
__device__ __forceinline__ void async_cp16(u16* lds, const u16* g) {
  __builtin_amdgcn_global_load_lds(
      (const __attribute__((address_space(1))) unsigned int*)g,
      (__attribute__((address_space(3))) unsigned int*)lds, 16, 0, 0);
}
__device__ __forceinline__ f32x16 fz16() {
  f32x16 z;
#pragma unroll
  for (int i = 0; i < 16; ++i) z[i] = 0.0f;
  return z;
}

// Fragment-linear layouts (lane l = hi*32+lo, e = 0..7):
//  weights [O][512]: fW(o,c) = (((o>>5)*8 + (c>>6))*4 + ((c>>4)&3))*512
//                              + (((c>>3)&1)*32 + (o&31))*8 + (c&7)
//  wo [512][256]:  fWO(c,k) = ((c>>5)*16 + (k>>4))*512 + (((k>>3)&1)*32 + (c&31))*8 + (k&7)
//  th [b][n][cb]:  (jq*4+kh)*512 + l*8 + e            (jq = n>>5)
//  ph [b][m][cb]:  (jm*4+kh)*512 + l*8 + e            (jm = m>>5)
//  vt [b][cg][m]:  ((ic*8+ct)*4+kh)*512 + l*8 + e     (ic=m>>6, ct=cg>>5, kh=(m>>4)&3)
//  O  [b][q][cg]:  (jq*16+f)*512 + l*8 + e            (f = cg>>4) — B-frag linear

// ---------------- weights fp32 -> bf16, tiled ----------------
__global__ __launch_bounds__(256) void cvt_all_kernel(
    const float* __restrict__ w_theta, const float* __restrict__ w_phi,
    const float* __restrict__ w_g, const float* __restrict__ w_out,
    const float* __restrict__ gamma, u16* __restrict__ dth, u16* __restrict__ dph,
    u16* __restrict__ dg, u16* __restrict__ dwo) {
  int i = blockIdx.x * 256 + threadIdx.x;
  if (i < 16384) {  // wth / wph : 64 x 512
    const float* s = (i < 8192) ? w_theta : w_phi;
    u16* d = (i < 8192) ? dth : dph;
    float scale = (i < 8192) ? LOG2E : 1.0f;
    int j = i & 8191;
    int o = j >> 7, c = (j & 127) * 4;
    float4 vv = *(const float4*)(s + (size_t)o * 512 + c);
    int idx = (((o >> 5) * 8 + (c >> 6)) * 4 + ((c >> 4) & 3)) * 512 +
              (((c >> 3) & 1) * 32 + (o & 31)) * 8 + (c & 7);
    u16x4 ot = {f2b(vv.x * scale), f2b(vv.y * scale), f2b(vv.z * scale), f2b(vv.w * scale)};
    *(u16x4*)(d + idx) = ot;
  } else if (i < 49152) {  // wg : 256 x 512
    int j = i - 16384;
    int o = j >> 7, c = (j & 127) * 4;
    float4 vv = *(const float4*)(w_g + (size_t)o * 512 + c);
    int idx = (((o >> 5) * 8 + (c >> 6)) * 4 + ((c >> 4) & 3)) * 512 +
              (((c >> 3) & 1) * 32 + (o & 31)) * 8 + (c & 7);
    u16x4 ot = {f2b(vv.x), f2b(vv.y), f2b(vv.z), f2b(vv.w)};
    *(u16x4*)(dg + idx) = ot;
  } else {  // wo : 512 x 256, gamma-prescaled
    int j = i - 49152;
    int o = j >> 6, k = (j & 63) * 4;
    float scale = gamma[0];
    float4 vv = *(const float4*)(w_out + (size_t)o * 256 + k);
    int idx = ((o >> 5) * 16 + (k >> 4)) * 512 +
              (((k >> 3) & 1) * 32 + (o & 31)) * 8 + (k & 7);
    u16x4 ot = {f2b(vv.x * scale), f2b(vv.y * scale), f2b(vv.z * scale), f2b(vv.w * scale)};
    *(u16x4*)(dwo + idx) = ot;
  }
}

// ---------------- fused prep: transpose + pool + theta/phi/g convs ----------------
// grid (32 nb, 16 b), 512 thr (8 waves). waves 0-3: theta; waves 4-7: g (+phi on 4,5).
__global__ __launch_bounds__(512) void prep_kernel(
    const float* __restrict__ x, const u16* __restrict__ wth,
    const u16* __restrict__ wph, const u16* __restrict__ wg,
    const float* __restrict__ bth, const float* __restrict__ bph,
    const float* __restrict__ bg, u16* __restrict__ th, u16* __restrict__ ph,
    u16* __restrict__ vt) {
  __shared__ u16 xb[128 * 68];   // [n][c-local], c-blocks XOR-swizzled
  __shared__ u16 xpt[32 * 68];   // [m][c-local]
  const int t = threadIdx.x;
  const int w = t >> 6, l = t & 63, lo = l & 31, hi = l >> 5;
  const int nb = blockIdx.x, b = blockIdx.y;
  const int n0 = nb * 128;
  const int lcol = (t & 31) * 4;  // n within 128
  const int lrow = t >> 5;        // c-row 0..15 (rows lrow+16i)

  f32x16 acc0 = fz16(), acc1 = fz16(), a_ph = fz16();

  float v[16];
  auto loadv = [&](int c0) {
#pragma unroll
    for (int i = 0; i < 4; ++i) {
      float4 f = *(const float4*)(x + ((size_t)(b * C_ + c0 + lrow + 16 * i)) * N_ + n0 + lcol);
      v[4*i] = f.x; v[4*i+1] = f.y; v[4*i+2] = f.z; v[4*i+3] = f.w;
    }
  };
  auto writeT = [&]() {
#pragma unroll
    for (int i = 0; i < 4; ++i) {
      int c = lrow + 16 * i;
      int blk = c >> 3;
#pragma unroll
      for (int k = 0; k < 4; ++k) {
        int n = lcol + k;
        int swz = ((n >> 2) ^ (n >> 5)) & 7;
        xb[n * 68 + ((blk ^ swz) * 8) + (c & 7)] = f2b(v[4*i+k]);
      }
    }
    float pA[4], pB[4];
#pragma unroll
    for (int i = 0; i < 4; ++i) {
      pA[i] = v[4*i] + v[4*i+1];
      pB[i] = v[4*i+2] + v[4*i+3];
    }
#pragma unroll
    for (int i = 0; i < 4; ++i) {
      pA[i] += __shfl_xor(pA[i], 16, 64);
      pB[i] += __shfl_xor(pB[i], 16, 64);
    }
    if ((t & 31) < 16) {
      int m0 = (t & 31) * 2;
#pragma unroll
      for (int i = 0; i < 4; ++i) {
        int c = lrow + 16 * i;
        xpt[m0 * 68 + c] = f2b(0.25f * pA[i]);
        xpt[(m0 + 1) * 68 + c] = f2b(0.25f * pB[i]);
      }
    }
  };
  auto domfma = [&](int c0b) {
    if (w < 4) {  // theta: A = xb rows 32w+lo
      const int n = 32 * w + lo;
      const int rbase = n * 68;
      const int nswz = ((n >> 2) ^ (n >> 5)) & 7;
#pragma unroll
      for (int kh = 0; kh < 4; ++kh) {
        bf16x8 xa = *(const bf16x8*)(&xb[rbase + (((2*kh + hi) ^ nswz) * 8)]);
        bf16x8 w0 = *(const bf16x8*)(wth + ((c0b) * 4 + kh) * 512 + l * 8);
        bf16x8 w1 = *(const bf16x8*)(wth + ((8 + c0b) * 4 + kh) * 512 + l * 8);
        acc0 = MFMA32(xa, w0, acc0, 0, 0, 0);
        acc1 = MFMA32(xa, w1, acc1, 0, 0, 0);
      }
    } else {  // g (+phi): B = xpt rows m=lo
      const int wg4 = w - 4;
      const u16* xpw = &xpt[lo * 68];
#pragma unroll
      for (int kh = 0; kh < 4; ++kh) {
        bf16x8 xp8 = *(const bf16x8*)(xpw + kh * 16 + hi * 8);
        bf16x8 g0 = *(const bf16x8*)(wg + ((16*wg4 + c0b) * 4 + kh) * 512 + l * 8);
        bf16x8 g1 = *(const bf16x8*)(wg + ((16*wg4 + 8 + c0b) * 4 + kh) * 512 + l * 8);
        acc0 = MFMA32(g0, xp8, acc0, 0, 0, 0);
        acc1 = MFMA32(g1, xp8, acc1, 0, 0, 0);
        if (wg4 < 2) {
          bf16x8 wp8 = *(const bf16x8*)(wph + ((wg4*8 + c0b) * 4 + kh) * 512 + l * 8);
          a_ph = MFMA32(xp8, wp8, a_ph, 0, 0, 0);
        }
      }
    }
  };

  loadv(0);
  for (int i = 0; i < 8; ++i) {
    if (i) __syncthreads();
    writeT();
    if (i < 7) loadv((i + 1) * 64);
    __syncthreads();
    domfma(i);
  }

  int rr[16];
#pragma unroll
  for (int r = 0; r < 16; ++r) rr[r] = (r & 3) + 8 * (r >> 2) + 4 * hi;

  if (w < 4) {  // th (tiled)
    u16* thb = th + (size_t)b * 262144;
#pragma unroll
    for (int r = 0; r < 16; ++r) {
      int sub = (((lo >> 3) & 1) * 32 + rr[r]) * 8 + (lo & 7);
      thb[((nb*4 + w)*4 + (lo >> 4)) * 512 + sub]     = f2b(acc0[r] + LOG2E * bth[lo]);
      thb[((nb*4 + w)*4 + 2 + (lo >> 4)) * 512 + sub] = f2b(acc1[r] + LOG2E * bth[32 + lo]);
    }
  } else {
    const int wg4 = w - 4;
    u16* vtb = vt + (size_t)b * 262144;
#pragma unroll
    for (int r = 0; r < 16; ++r) {  // vt (tiled)
      int cg0 = 64 * wg4 + rr[r];
      int sub = (((lo >> 3) & 1) * 32 + rr[r]) * 8 + (lo & 7);
      int kk = (nb & 1) * 2 + (lo >> 4);
      vtb[(((nb >> 1) * 8 + 2*wg4) * 4 + kk) * 512 + sub]     = f2b(acc0[r] + bg[cg0]);
      vtb[(((nb >> 1) * 8 + 2*wg4 + 1) * 4 + kk) * 512 + sub] = f2b(acc1[r] + bg[cg0 + 32]);
    }
    if (wg4 < 2) {  // ph (tiled)
      u16* phb = ph + (size_t)b * 65536;
#pragma unroll
      for (int r = 0; r < 16; ++r) {
        int sub = (((lo >> 3) & 1) * 32 + rr[r]) * 8 + (lo & 7);
        phb[(nb*4 + 2*wg4 + (lo >> 4)) * 512 + sub] = f2b(a_ph[r] + bph[32*wg4 + lo]);
      }
    }
  }
}

// ---------------- attention core: flash loop -> normalized O (tiled) ----------------
// grid (32,16) XCD-swizzled; 512 thr = 4 q-pairs x 2 cg-halves; 128 q/block.
// 32 m-chunks of 32; 4 bufs x 20KB { V[16 rows][512] | phi[4 rows][512] };
// stage 2 chunks ahead, 3 loads/wave/stage, vmcnt(3) at barriers (T3/T4).
__global__ __launch_bounds__(512, 4) void attn_core_kernel(
    const u16* __restrict__ th, const u16* __restrict__ ph,
    const u16* __restrict__ vt, u16* __restrict__ Og) {
  __shared__ u16 smem[40960];  // 80KB

  const int t = threadIdx.x;
  const int w = t >> 6, l = t & 63;
  const int p = w & 3, h = w >> 2;
  const int flat = blockIdx.y * 32 + blockIdx.x;
  const int nf = (flat & 7) * 64 + (flat >> 3);  // bijective XCD swizzle
  const int b = nf >> 5, nb5 = nf & 31;
  const int jqt = nb5 * 4 + p;  // 32q-tile index in batch

  const u16* thb = th + (size_t)b * 262144;
  const u16* phb = ph + (size_t)b * 65536;
  const u16* vtb = vt + (size_t)b * 262144;

  bf16x8 thB[4];
#pragma unroll
  for (int kh = 0; kh < 4; ++kh)
    thB[kh] = *(const bf16x8*)(thb + (jqt * 4 + kh) * 512 + l * 8);

  f32x16 acc[4];
#pragma unroll
  for (int ct = 0; ct < 4; ++ct) acc[ct] = fz16();
  float sp[4] = {0.0f, 0.0f, 0.0f, 0.0f};

  // stage chunk k into buf k&3: 2 V loads + 1 phi load per thread (3/wave).
  // V local row r = ct*2 + khl (r = w+8i, wave-uniform); inner = l*8.
  auto stage = [&](int k) {
    const int ic = k >> 1, jml2 = (k & 1) * 2;
    u16* base = &smem[(k & 3) * 10240];
#pragma unroll
    for (int i = 0; i < 2; ++i) {
      const int r = w + 8 * i;
      const u16* src = vtb + (size_t)((ic * 8 + (r >> 1)) * 4 + jml2 + (r & 1)) * 512 + l * 8;
      async_cp16(base + r * 512 + l * 8, src);
    }
    {  // phi 4KB, duplicated across thread-halves (same bytes, benign)
      const int o2 = (t & 255) * 8;
      async_cp16(base + 8192 + o2, phb + (size_t)k * 2048 + o2);
    }
  };

  stage(0);
  stage(1);
  asm volatile("s_waitcnt vmcnt(3)" ::: "memory");  // chunk 0 landed; 1 in flight
  __builtin_amdgcn_sched_barrier(0);
  __builtin_amdgcn_s_barrier();

  for (int k = 0; k < 32; ++k) {
    if (k < 30) stage(k + 2);

    const u16* Vs = &smem[(k & 3) * 10240];
    const u16* Ps = Vs + 8192;

    // QK^T swapped: S^T (q = lane lo, m-local over regs); phi from LDS
    f32x16 S = fz16();
#pragma unroll
    for (int kh = 0; kh < 4; ++kh) {
      bf16x8 pf = *(const bf16x8*)(Ps + kh * 512 + l * 8);
      S = MFMA32(pf, thB[kh], S, 0, 0, 0);
    }

    // P = exp2(S - FIXMAX) (exact pow2, cancels in normalize); deferred sum
#pragma unroll
    for (int i = 0; i < 16; ++i) {
      S[i] = exp2v(S[i] - FIXMAX);
      sp[i & 3] += S[i];
    }

    // P -> bf16 B-frags (cvt_pk + permlane32_swap)
    bf16x8 Pf[2];
#pragma unroll
    for (int s = 0; s < 2; ++s) {
      unsigned a0 = cvtpk(S[8*s+0], S[8*s+1]);
      unsigned a1 = cvtpk(S[8*s+2], S[8*s+3]);
      unsigned a2 = cvtpk(S[8*s+4], S[8*s+5]);
      unsigned a3 = cvtpk(S[8*s+6], S[8*s+7]);
      permswap(a0, a2);
      permswap(a1, a3);
      i32x4 wv = {(int)a0, (int)a1, (int)a2, (int)a3};
      Pf[s] = __builtin_bit_cast(bf16x8, wv);
    }

    // PV (transposed): acc[ct2] += V^T-frag (A, cg rows) @ Pf (B, col=q)
    __builtin_amdgcn_s_setprio(1);
#pragma unroll
    for (int ct2 = 0; ct2 < 4; ++ct2) {
      const u16* vp = Vs + (4 * h + ct2) * 1024 + l * 8;
      bf16x8 vf0 = *(const bf16x8*)(vp);
      bf16x8 vf1 = *(const bf16x8*)(vp + 512);
      acc[ct2] = MFMA32(vf0, Pf[0], acc[ct2], 0, 0, 0);
      acc[ct2] = MFMA32(vf1, Pf[1], acc[ct2], 0, 0, 0);
    }
    __builtin_amdgcn_s_setprio(0);

    // counted wait: stage(k+1) proven landed; stage(k+2)'s 3 stay in flight
    if (k < 30) {
      asm volatile("s_waitcnt vmcnt(3)" ::: "memory");
      __builtin_amdgcn_sched_barrier(0);
      __builtin_amdgcn_s_barrier();
    } else if (k == 30) {
      asm volatile("s_waitcnt vmcnt(0)" ::: "memory");
      __builtin_amdgcn_sched_barrier(0);
      __builtin_amdgcn_s_barrier();
    }
  }

  float lsum = (sp[0] + sp[1]) + (sp[2] + sp[3]);
  lsum += __shfl_xor(lsum, 32, 64);
  const float linv = 1.0f / lsum;

  // normalize + pack O -> global (frag-linear: (jqt*16+f)*512 + l*8)
  u16* Ob = Og + (size_t)b * 1048576 + (size_t)jqt * 16 * 512;
#pragma unroll
  for (int ct2 = 0; ct2 < 4; ++ct2) {
    f32x16& A = acc[ct2];
#pragma unroll
    for (int s = 0; s < 2; ++s) {
      unsigned a0 = cvtpk(A[8*s+0]*linv, A[8*s+1]*linv);
      unsigned a1 = cvtpk(A[8*s+2]*linv, A[8*s+3]*linv);
      unsigned a2 = cvtpk(A[8*s+4]*linv, A[8*s+5]*linv);
      unsigned a3 = cvtpk(A[8*s+6]*linv, A[8*s+7]*linv);
      permswap(a0, a2);
      permswap(a1, a3);
      i32x4 wv = {(int)a0, (int)a1, (int)a2, (int)a3};
      int f = 8 * h + 2 * ct2 + s;
      *(bf16x8*)(Ob + f * 512 + l * 8) = __builtin_bit_cast(bf16x8, wv);
    }
  }
}

// ---------------- streaming out-conv + residual ----------------
// grid (32,16) XCD-swizzled (same mapping as core => O L2-local); 512 thr,
// wave (p,h): q-tile p (32 q), c-half h. No LDS, no barriers.
__global__ __launch_bounds__(512, 4) void outconv_kernel(
    const u16* __restrict__ Og, const u16* __restrict__ wo,
    const float* __restrict__ b_out, const float* __restrict__ gamma,
    const float* __restrict__ x, float* __restrict__ out) {
  const int t = threadIdx.x;
  const int w = t >> 6, l = t & 63, lo = l & 31, hi = l >> 5;
  const int p = w & 3, h = w >> 2;
  const int flat = blockIdx.y * 32 + blockIdx.x;
  const int nf = (flat & 7) * 64 + (flat >> 3);
  const int b = nf >> 5, nb5 = nf & 31;
  const int jqt = nb5 * 4 + p;
  const int qp = jqt * 32;

  // O B-frags (k=cg 0..255, col=q)
  const u16* Ob = Og + (size_t)b * 1048576 + (size_t)jqt * 16 * 512;
  bf16x8 Of[16];
#pragma unroll
  for (int f = 0; f < 16; ++f)
    Of[f] = *(const bf16x8*)(Ob + f * 512 + l * 8);

  int rr[16];
#pragma unroll
  for (int r = 0; r < 16; ++r) rr[r] = (r & 3) + 8 * (r >> 2) + 4 * hi;

  const float gamma0 = gamma[0];
  for (int ctc = 0; ctc < 8; ++ctc) {
    f32x16 facc = fz16();
    const u16* wp = wo + (size_t)((8 * h + ctc) * 16) * 512 + l * 8;
#pragma unroll
    for (int f = 0; f < 16; ++f) {
      bf16x8 wfr = *(const bf16x8*)(wp + f * 512);
      facc = MFMA32(wfr, Of[f], facc, 0, 0, 0);  // wo gamma-prescaled
    }
#pragma unroll
    for (int r = 0; r < 16; ++r) {
      int c = 256 * h + 32 * ctc + rr[r];
      size_t idx = ((size_t)(b * C_ + c)) * N_ + qp + lo;
      float xv = __builtin_nontemporal_load(&x[idx]);
      __builtin_nontemporal_store(facc[r] + gamma0 * b_out[c] + xv, &out[idx]);
    }
  }
}

extern "C" void kernel_launch(void* const* d_in, const int* in_sizes, int n_in,
                              void* d_out, int out_size, void* d_ws, size_t ws_size,
                              hipStream_t stream) {
  (void)in_sizes; (void)n_in; (void)out_size; (void)ws_size;
  const float* x       = (const float*)d_in[0];
  const float* w_theta = (const float*)d_in[1];
  const float* b_theta = (const float*)d_in[2];
  const float* w_phi   = (const float*)d_in[3];
  const float* b_phi   = (const float*)d_in[4];
  const float* w_g     = (const float*)d_in[5];
  const float* b_g     = (const float*)d_in[6];
  const float* w_out   = (const float*)d_in[7];
  const float* b_out   = (const float*)d_in[8];
  const float* gamma   = (const float*)d_in[9];
  float* out = (float*)d_out;

  char* ws = (char*)d_ws;
  u16* th  = (u16*)(ws);               // 16*262144*2 = 8,388,608
  u16* ph  = (u16*)(ws + 8388608);     // 16*65536*2  = 2,097,152
  u16* vt  = (u16*)(ws + 10485760);    // 16*262144*2 = 8,388,608
  u16* wth = (u16*)(ws + 18874368);    // 65,536
  u16* wph = (u16*)(ws + 18939904);    // 65,536
  u16* wg  = (u16*)(ws + 19005440);    // 262,144
  u16* wo  = (u16*)(ws + 19267584);    // 262,144 (end 19,529,728)
  u16* Og  = (u16*)(ws + 19529728);    // 16*1048576*2 = 33,554,432 (end 53,084,160)

  cvt_all_kernel<<<320, 256, 0, stream>>>(w_theta, w_phi, w_g, w_out, gamma,
                                          wth, wph, wg, wo);
  prep_kernel<<<dim3(32, 16), 512, 0, stream>>>(x, wth, wph, wg, b_theta, b_phi,
                                                b_g, th, ph, vt);
  attn_core_kernel<<<dim3(32, 16), 512, 0, stream>>>(th, ph, vt, Og);
  outconv_kernel<<<dim3(32, 16), 512, 0, stream>>>(Og, wo, b_out, gamma, x, out);
}

// Round 13
// 164.625 us; speedup vs baseline: 1.4806x; 1.0194x over previous
//
#include <hip/hip_runtime.h>
#include <math.h>

// Conv2dSelfAttention MI355X — round 13: 64q/wave attn_core (2 q-tiles/wave).
// phi+V LDS reads amortized 2x (pf reused across both q-tiles; each V frag
// feeds 2 PV MFMAs). 256 blocks = 1/CU; counted-vmcnt quad-buffer kept.
// B=16, C=512, N=4096, M=1024, CB=64, CG=256.

typedef unsigned short u16;
typedef short bf16x8 __attribute__((ext_vector_type(8)));
typedef float f32x16 __attribute__((ext_vector_type(16)));
typedef u16 u16x4 __attribute__((ext_vector_type(4)));
typedef int i32x4 __attribute__((ext_vector_type(4)));

#define MFMA32 __builtin_amdgcn_mfma_f32_32x32x16_bf16
#define B_ 16
#define C_ 512
#define N_ 4096
#define M_ 1024
#define LOG2E 1.44269504088896f
#define FIXMAX 8.0f

__device__ __forceinline__ u16 f2b(float f) {  // fp32 -> bf16 RNE
  unsigned u = __float_as_uint(f);
  return (u16)((u + 0x7FFFu + ((u >> 16) & 1u)) >> 16);
}
__device__ __forceinline__ unsigned cvtpk(float a, float b) {  // lo=a, hi=b
  unsigned r;
  asm("v_cvt_pk_bf16_f32 %0, %1, %2" : "=v"(r) : "v"(a), "v"(b));
  return r;
}
__device__ __forceinline__ void permswap(unsigned &a, unsigned &b) {
  asm("v_permlane32_swap_b32 %0, %1" : "+v"(a), "+v"(b));
}
__device__ __forceinline__ float exp2v(float a) {
  float r;
  asm("v_exp_f32 %0, %1" : "=v"(r) : "v"(a));
  return r;
}
__device__ __forceinline__ void async_cp16(u16* lds, const u16* g) {
  __builtin_amdgcn_global_load_lds(
      (const __attribute__((address_space(1))) unsigned int*)g,
      (__attribute__((address_space(3))) unsigned int*)lds, 16, 0, 0);
}
__device__ __forceinline__ f32x16 fz16() {
  f32x16 z;
#pragma unroll
  for (int i = 0; i < 16; ++i) z[i] = 0.0f;
  return z;
}

// Fragment-linear layouts (lane l = hi*32+lo, e = 0..7):
//  weights [O][512]: fW(o,c) = (((o>>5)*8 + (c>>6))*4 + ((c>>4)&3))*512
//                              + (((c>>3)&1)*32 + (o&31))*8 + (c&7)
//  wo [512][256]:  fWO(c,k) = ((c>>5)*16 + (k>>4))*512 + (((k>>3)&1)*32 + (c&31))*8 + (k&7)
//  th [b][n][cb]:  (jq*4+kh)*512 + l*8 + e            (jq = n>>5)
//  ph [b][m][cb]:  (jm*4+kh)*512 + l*8 + e            (jm = m>>5)
//  vt [b][cg][m]:  ((ic*8+ct)*4+kh)*512 + l*8 + e     (ic=m>>6, ct=cg>>5, kh=(m>>4)&3)
//  O  [b][q][cg]:  (jq*16+f)*512 + l*8 + e            (f = cg>>4) — B-frag linear

// ---------------- weights fp32 -> bf16, tiled ----------------
__global__ __launch_bounds__(256) void cvt_all_kernel(
    const float* __restrict__ w_theta, const float* __restrict__ w_phi,
    const float* __restrict__ w_g, const float* __restrict__ w_out,
    const float* __restrict__ gamma, u16* __restrict__ dth, u16* __restrict__ dph,
    u16* __restrict__ dg, u16* __restrict__ dwo) {
  int i = blockIdx.x * 256 + threadIdx.x;
  if (i < 16384) {  // wth / wph : 64 x 512
    const float* s = (i < 8192) ? w_theta : w_phi;
    u16* d = (i < 8192) ? dth : dph;
    float scale = (i < 8192) ? LOG2E : 1.0f;
    int j = i & 8191;
    int o = j >> 7, c = (j & 127) * 4;
    float4 vv = *(const float4*)(s + (size_t)o * 512 + c);
    int idx = (((o >> 5) * 8 + (c >> 6)) * 4 + ((c >> 4) & 3)) * 512 +
              (((c >> 3) & 1) * 32 + (o & 31)) * 8 + (c & 7);
    u16x4 ot = {f2b(vv.x * scale), f2b(vv.y * scale), f2b(vv.z * scale), f2b(vv.w * scale)};
    *(u16x4*)(d + idx) = ot;
  } else if (i < 49152) {  // wg : 256 x 512
    int j = i - 16384;
    int o = j >> 7, c = (j & 127) * 4;
    float4 vv = *(const float4*)(w_g + (size_t)o * 512 + c);
    int idx = (((o >> 5) * 8 + (c >> 6)) * 4 + ((c >> 4) & 3)) * 512 +
              (((c >> 3) & 1) * 32 + (o & 31)) * 8 + (c & 7);
    u16x4 ot = {f2b(vv.x), f2b(vv.y), f2b(vv.z), f2b(vv.w)};
    *(u16x4*)(dg + idx) = ot;
  } else {  // wo : 512 x 256, gamma-prescaled
    int j = i - 49152;
    int o = j >> 6, k = (j & 63) * 4;
    float scale = gamma[0];
    float4 vv = *(const float4*)(w_out + (size_t)o * 256 + k);
    int idx = ((o >> 5) * 16 + (k >> 4)) * 512 +
              (((k >> 3) & 1) * 32 + (o & 31)) * 8 + (k & 7);
    u16x4 ot = {f2b(vv.x * scale), f2b(vv.y * scale), f2b(vv.z * scale), f2b(vv.w * scale)};
    *(u16x4*)(dwo + idx) = ot;
  }
}

// ---------------- fused prep: transpose + pool + theta/phi/g convs ----------------
// grid (32 nb, 16 b), 512 thr (8 waves). waves 0-3: theta; waves 4-7: g (+phi on 4,5).
__global__ __launch_bounds__(512) void prep_kernel(
    const float* __restrict__ x, const u16* __restrict__ wth,
    const u16* __restrict__ wph, const u16* __restrict__ wg,
    const float* __restrict__ bth, const float* __restrict__ bph,
    const float* __restrict__ bg, u16* __restrict__ th, u16* __restrict__ ph,
    u16* __restrict__ vt) {
  __shared__ u16 xb[128 * 68];   // [n][c-local], c-blocks XOR-swizzled
  __shared__ u16 xpt[32 * 68];   // [m][c-local]
  const int t = threadIdx.x;
  const int w = t >> 6, l = t & 63, lo = l & 31, hi = l >> 5;
  const int nb = blockIdx.x, b = blockIdx.y;
  const int n0 = nb * 128;
  const int lcol = (t & 31) * 4;  // n within 128
  const int lrow = t >> 5;        // c-row 0..15 (rows lrow+16i)

  f32x16 acc0 = fz16(), acc1 = fz16(), a_ph = fz16();

  float v[16];
  auto loadv = [&](int c0) {
#pragma unroll
    for (int i = 0; i < 4; ++i) {
      float4 f = *(const float4*)(x + ((size_t)(b * C_ + c0 + lrow + 16 * i)) * N_ + n0 + lcol);
      v[4*i] = f.x; v[4*i+1] = f.y; v[4*i+2] = f.z; v[4*i+3] = f.w;
    }
  };
  auto writeT = [&]() {
#pragma unroll
    for (int i = 0; i < 4; ++i) {
      int c = lrow + 16 * i;
      int blk = c >> 3;
#pragma unroll
      for (int k = 0; k < 4; ++k) {
        int n = lcol + k;
        int swz = ((n >> 2) ^ (n >> 5)) & 7;
        xb[n * 68 + ((blk ^ swz) * 8) + (c & 7)] = f2b(v[4*i+k]);
      }
    }
    float pA[4], pB[4];
#pragma unroll
    for (int i = 0; i < 4; ++i) {
      pA[i] = v[4*i] + v[4*i+1];
      pB[i] = v[4*i+2] + v[4*i+3];
    }
#pragma unroll
    for (int i = 0; i < 4; ++i) {
      pA[i] += __shfl_xor(pA[i], 16, 64);
      pB[i] += __shfl_xor(pB[i], 16, 64);
    }
    if ((t & 31) < 16) {
      int m0 = (t & 31) * 2;
#pragma unroll
      for (int i = 0; i < 4; ++i) {
        int c = lrow + 16 * i;
        xpt[m0 * 68 + c] = f2b(0.25f * pA[i]);
        xpt[(m0 + 1) * 68 + c] = f2b(0.25f * pB[i]);
      }
    }
  };
  auto domfma = [&](int c0b) {
    if (w < 4) {  // theta: A = xb rows 32w+lo
      const int n = 32 * w + lo;
      const int rbase = n * 68;
      const int nswz = ((n >> 2) ^ (n >> 5)) & 7;
#pragma unroll
      for (int kh = 0; kh < 4; ++kh) {
        bf16x8 xa = *(const bf16x8*)(&xb[rbase + (((2*kh + hi) ^ nswz) * 8)]);
        bf16x8 w0 = *(const bf16x8*)(wth + ((c0b) * 4 + kh) * 512 + l * 8);
        bf16x8 w1 = *(const bf16x8*)(wth + ((8 + c0b) * 4 + kh) * 512 + l * 8);
        acc0 = MFMA32(xa, w0, acc0, 0, 0, 0);
        acc1 = MFMA32(xa, w1, acc1, 0, 0, 0);
      }
    } else {  // g (+phi): B = xpt rows m=lo
      const int wg4 = w - 4;
      const u16* xpw = &xpt[lo * 68];
#pragma unroll
      for (int kh = 0; kh < 4; ++kh) {
        bf16x8 xp8 = *(const bf16x8*)(xpw + kh * 16 + hi * 8);
        bf16x8 g0 = *(const bf16x8*)(wg + ((16*wg4 + c0b) * 4 + kh) * 512 + l * 8);
        bf16x8 g1 = *(const bf16x8*)(wg + ((16*wg4 + 8 + c0b) * 4 + kh) * 512 + l * 8);
        acc0 = MFMA32(g0, xp8, acc0, 0, 0, 0);
        acc1 = MFMA32(g1, xp8, acc1, 0, 0, 0);
        if (wg4 < 2) {
          bf16x8 wp8 = *(const bf16x8*)(wph + ((wg4*8 + c0b) * 4 + kh) * 512 + l * 8);
          a_ph = MFMA32(xp8, wp8, a_ph, 0, 0, 0);
        }
      }
    }
  };

  loadv(0);
  for (int i = 0; i < 8; ++i) {
    if (i) __syncthreads();
    writeT();
    if (i < 7) loadv((i + 1) * 64);
    __syncthreads();
    domfma(i);
  }

  int rr[16];
#pragma unroll
  for (int r = 0; r < 16; ++r) rr[r] = (r & 3) + 8 * (r >> 2) + 4 * hi;

  if (w < 4) {  // th (tiled)
    u16* thb = th + (size_t)b * 262144;
#pragma unroll
    for (int r = 0; r < 16; ++r) {
      int sub = (((lo >> 3) & 1) * 32 + rr[r]) * 8 + (lo & 7);
      thb[((nb*4 + w)*4 + (lo >> 4)) * 512 + sub]     = f2b(acc0[r] + LOG2E * bth[lo]);
      thb[((nb*4 + w)*4 + 2 + (lo >> 4)) * 512 + sub] = f2b(acc1[r] + LOG2E * bth[32 + lo]);
    }
  } else {
    const int wg4 = w - 4;
    u16* vtb = vt + (size_t)b * 262144;
#pragma unroll
    for (int r = 0; r < 16; ++r) {  // vt (tiled)
      int cg0 = 64 * wg4 + rr[r];
      int sub = (((lo >> 3) & 1) * 32 + rr[r]) * 8 + (lo & 7);
      int kk = (nb & 1) * 2 + (lo >> 4);
      vtb[(((nb >> 1) * 8 + 2*wg4) * 4 + kk) * 512 + sub]     = f2b(acc0[r] + bg[cg0]);
      vtb[(((nb >> 1) * 8 + 2*wg4 + 1) * 4 + kk) * 512 + sub] = f2b(acc1[r] + bg[cg0 + 32]);
    }
    if (wg4 < 2) {  // ph (tiled)
      u16* phb = ph + (size_t)b * 65536;
#pragma unroll
      for (int r = 0; r < 16; ++r) {
        int sub = (((lo >> 3) & 1) * 32 + rr[r]) * 8 + (lo & 7);
        phb[(nb*4 + 2*wg4 + (lo >> 4)) * 512 + sub] = f2b(a_ph[r] + bph[32*wg4 + lo]);
      }
    }
  }
}

// ---------------- attention core: flash loop -> normalized O (tiled) ----------------
// grid (16,16) = 256 blocks (1/CU); 512 thr = 4 q-pairs x 2 cg-halves.
// Wave owns TWO 32-q tiles (jA, jB): phi frags reused across both QKs; each
// V frag feeds 2 PV MFMAs. 32 m-chunks; quad-buffer counted-vmcnt (T3/T4).
__global__ __launch_bounds__(512, 2) void attn_core_kernel(
    const u16* __restrict__ th, const u16* __restrict__ ph,
    const u16* __restrict__ vt, u16* __restrict__ Og) {
  __shared__ u16 smem[49152];  // 96KB declared (forces 1 block/CU); 80KB used

  const int t = threadIdx.x;
  const int w = t >> 6, l = t & 63;
  const int p = w & 3, h = w >> 2;
  const int flat = blockIdx.y * 16 + blockIdx.x;
  const int nf = (flat & 7) * 32 + (flat >> 3);  // XCD-chunked bijection (256=8*32)
  const int b = nf >> 4, nb6 = nf & 15;          // 256-q super-tile
  const int jA = nb6 * 8 + p * 2, jB = jA + 1;   // this wave's two 32-q tiles

  const u16* thb = th + (size_t)b * 262144;
  const u16* phb = ph + (size_t)b * 65536;
  const u16* vtb = vt + (size_t)b * 262144;

  bf16x8 thA[4], thBt[4];
#pragma unroll
  for (int kh = 0; kh < 4; ++kh) {
    thA[kh]  = *(const bf16x8*)(thb + (jA * 4 + kh) * 512 + l * 8);
    thBt[kh] = *(const bf16x8*)(thb + (jB * 4 + kh) * 512 + l * 8);
  }

  f32x16 accA[4], accB[4];
#pragma unroll
  for (int ct = 0; ct < 4; ++ct) { accA[ct] = fz16(); accB[ct] = fz16(); }
  float spA[4] = {0.f, 0.f, 0.f, 0.f}, spB[4] = {0.f, 0.f, 0.f, 0.f};

  // stage chunk k into buf k&3: 2 V loads + 1 phi load per thread.
  auto stage = [&](int k) {
    const int ic = k >> 1, jml2 = (k & 1) * 2;
    u16* base = &smem[(k & 3) * 10240];
#pragma unroll
    for (int i = 0; i < 2; ++i) {
      const int r = w + 8 * i;
      const u16* src = vtb + (size_t)((ic * 8 + (r >> 1)) * 4 + jml2 + (r & 1)) * 512 + l * 8;
      async_cp16(base + r * 512 + l * 8, src);
    }
    {  // phi 4KB, duplicated across thread-halves (same bytes, benign)
      const int o2 = (t & 255) * 8;
      async_cp16(base + 8192 + o2, phb + (size_t)k * 2048 + o2);
    }
  };

  auto packPf = [&](f32x16& S, bf16x8* Pf) {
#pragma unroll
    for (int s = 0; s < 2; ++s) {
      unsigned a0 = cvtpk(S[8*s+0], S[8*s+1]);
      unsigned a1 = cvtpk(S[8*s+2], S[8*s+3]);
      unsigned a2 = cvtpk(S[8*s+4], S[8*s+5]);
      unsigned a3 = cvtpk(S[8*s+6], S[8*s+7]);
      permswap(a0, a2);
      permswap(a1, a3);
      i32x4 wv = {(int)a0, (int)a1, (int)a2, (int)a3};
      Pf[s] = __builtin_bit_cast(bf16x8, wv);
    }
  };

  stage(0);
  stage(1);
  asm volatile("s_waitcnt vmcnt(3)" ::: "memory");  // chunk 0 landed; 1 in flight
  __builtin_amdgcn_sched_barrier(0);
  __builtin_amdgcn_s_barrier();

  for (int k = 0; k < 32; ++k) {
    if (k < 30) stage(k + 2);

    const u16* Vs = &smem[(k & 3) * 10240];
    const u16* Ps = Vs + 8192;

    // phi frags read ONCE, feed both q-tiles' QK
    bf16x8 pf[4];
#pragma unroll
    for (int kh = 0; kh < 4; ++kh)
      pf[kh] = *(const bf16x8*)(Ps + kh * 512 + l * 8);

    // QK + softmax, tile A
    f32x16 S = fz16();
#pragma unroll
    for (int kh = 0; kh < 4; ++kh) S = MFMA32(pf[kh], thA[kh], S, 0, 0, 0);
#pragma unroll
    for (int i = 0; i < 16; ++i) {
      S[i] = exp2v(S[i] - FIXMAX);
      spA[i & 3] += S[i];
    }
    bf16x8 PfA[2];
    packPf(S, PfA);

    // QK + softmax, tile B (pf reused — no LDS reads)
    f32x16 S2 = fz16();
#pragma unroll
    for (int kh = 0; kh < 4; ++kh) S2 = MFMA32(pf[kh], thBt[kh], S2, 0, 0, 0);
#pragma unroll
    for (int i = 0; i < 16; ++i) {
      S2[i] = exp2v(S2[i] - FIXMAX);
      spB[i & 3] += S2[i];
    }
    bf16x8 PfB[2];
    packPf(S2, PfB);

    // PV: each V frag feeds both tiles (2x MFMA per ds_read)
    __builtin_amdgcn_s_setprio(1);
#pragma unroll
    for (int ct2 = 0; ct2 < 4; ++ct2) {
      const u16* vp = Vs + (4 * h + ct2) * 1024 + l * 8;
      bf16x8 vf0 = *(const bf16x8*)(vp);
      bf16x8 vf1 = *(const bf16x8*)(vp + 512);
      accA[ct2] = MFMA32(vf0, PfA[0], accA[ct2], 0, 0, 0);
      accA[ct2] = MFMA32(vf1, PfA[1], accA[ct2], 0, 0, 0);
      accB[ct2] = MFMA32(vf0, PfB[0], accB[ct2], 0, 0, 0);
      accB[ct2] = MFMA32(vf1, PfB[1], accB[ct2], 0, 0, 0);
    }
    __builtin_amdgcn_s_setprio(0);

    // counted wait: stage(k+1) proven landed; stage(k+2)'s 3 stay in flight
    if (k < 30) {
      asm volatile("s_waitcnt vmcnt(3)" ::: "memory");
      __builtin_amdgcn_sched_barrier(0);
      __builtin_amdgcn_s_barrier();
    } else if (k == 30) {
      asm volatile("s_waitcnt vmcnt(0)" ::: "memory");
      __builtin_amdgcn_sched_barrier(0);
      __builtin_amdgcn_s_barrier();
    }
  }

  float lA = (spA[0] + spA[1]) + (spA[2] + spA[3]);
  lA += __shfl_xor(lA, 32, 64);
  const float liA = 1.0f / lA;
  float lB = (spB[0] + spB[1]) + (spB[2] + spB[3]);
  lB += __shfl_xor(lB, 32, 64);
  const float liB = 1.0f / lB;

  // normalize + pack O -> global (frag-linear: (jq*16+f)*512 + l*8)
  auto packO = [&](f32x16* acc, float li, int jq) {
    u16* Ob = Og + (size_t)b * 1048576 + (size_t)jq * 16 * 512;
#pragma unroll
    for (int ct2 = 0; ct2 < 4; ++ct2) {
      f32x16& A = acc[ct2];
#pragma unroll
      for (int s = 0; s < 2; ++s) {
        unsigned a0 = cvtpk(A[8*s+0]*li, A[8*s+1]*li);
        unsigned a1 = cvtpk(A[8*s+2]*li, A[8*s+3]*li);
        unsigned a2 = cvtpk(A[8*s+4]*li, A[8*s+5]*li);
        unsigned a3 = cvtpk(A[8*s+6]*li, A[8*s+7]*li);
        permswap(a0, a2);
        permswap(a1, a3);
        i32x4 wv = {(int)a0, (int)a1, (int)a2, (int)a3};
        int f = 8 * h + 2 * ct2 + s;
        *(bf16x8*)(Ob + f * 512 + l * 8) = __builtin_bit_cast(bf16x8, wv);
      }
    }
  };
  packO(accA, liA, jA);
  packO(accB, liB, jB);
}

// ---------------- streaming out-conv + residual ----------------
// grid (32,16) XCD-swizzled; 512 thr, wave (p,h): q-tile p (32 q), c-half h.
__global__ __launch_bounds__(512, 4) void outconv_kernel(
    const u16* __restrict__ Og, const u16* __restrict__ wo,
    const float* __restrict__ b_out, const float* __restrict__ gamma,
    const float* __restrict__ x, float* __restrict__ out) {
  const int t = threadIdx.x;
  const int w = t >> 6, l = t & 63, lo = l & 31, hi = l >> 5;
  const int p = w & 3, h = w >> 2;
  const int flat = blockIdx.y * 32 + blockIdx.x;
  const int nf = (flat & 7) * 64 + (flat >> 3);
  const int b = nf >> 5, nb5 = nf & 31;
  const int jqt = nb5 * 4 + p;
  const int qp = jqt * 32;

  // O B-frags (k=cg 0..255, col=q)
  const u16* Ob = Og + (size_t)b * 1048576 + (size_t)jqt * 16 * 512;
  bf16x8 Of[16];
#pragma unroll
  for (int f = 0; f < 16; ++f)
    Of[f] = *(const bf16x8*)(Ob + f * 512 + l * 8);

  int rr[16];
#pragma unroll
  for (int r = 0; r < 16; ++r) rr[r] = (r & 3) + 8 * (r >> 2) + 4 * hi;

  const float gamma0 = gamma[0];
  for (int ctc = 0; ctc < 8; ++ctc) {
    f32x16 facc = fz16();
    const u16* wp = wo + (size_t)((8 * h + ctc) * 16) * 512 + l * 8;
#pragma unroll
    for (int f = 0; f < 16; ++f) {
      bf16x8 wfr = *(const bf16x8*)(wp + f * 512);
      facc = MFMA32(wfr, Of[f], facc, 0, 0, 0);  // wo gamma-prescaled
    }
#pragma unroll
    for (int r = 0; r < 16; ++r) {
      int c = 256 * h + 32 * ctc + rr[r];
      size_t idx = ((size_t)(b * C_ + c)) * N_ + qp + lo;
      float xv = __builtin_nontemporal_load(&x[idx]);
      __builtin_nontemporal_store(facc[r] + gamma0 * b_out[c] + xv, &out[idx]);
    }
  }
}

extern "C" void kernel_launch(void* const* d_in, const int* in_sizes, int n_in,
                              void* d_out, int out_size, void* d_ws, size_t ws_size,
                              hipStream_t stream) {
  (void)in_sizes; (void)n_in; (void)out_size; (void)ws_size;
  const float* x       = (const float*)d_in[0];
  const float* w_theta = (const float*)d_in[1];
  const float* b_theta = (const float*)d_in[2];
  const float* w_phi   = (const float*)d_in[3];
  const float* b_phi   = (const float*)d_in[4];
  const float* w_g     = (const float*)d_in[5];
  const float* b_g     = (const float*)d_in[6];
  const float* w_out   = (const float*)d_in[7];
  const float* b_out   = (const float*)d_in[8];
  const float* gamma   = (const float*)d_in[9];
  float* out = (float*)d_out;

  char* ws = (char*)d_ws;
  u16* th  = (u16*)(ws);               // 16*262144*2 = 8,388,608
  u16* ph  = (u16*)(ws + 8388608);     // 16*65536*2  = 2,097,152
  u16* vt  = (u16*)(ws + 10485760);    // 16*262144*2 = 8,388,608
  u16* wth = (u16*)(ws + 18874368);    // 65,536
  u16* wph = (u16*)(ws + 18939904);    // 65,536
  u16* wg  = (u16*)(ws + 19005440);    // 262,144
  u16* wo  = (u16*)(ws + 19267584);    // 262,144 (end 19,529,728)
  u16* Og  = (u16*)(ws + 19529728);    // 16*1048576*2 = 33,554,432 (end 53,084,160)

  cvt_all_kernel<<<320, 256, 0, stream>>>(w_theta, w_phi, w_g, w_out, gamma,
                                          wth, wph, wg, wo);
  prep_kernel<<<dim3(32, 16), 512, 0, stream>>>(x, wth, wph, wg, b_theta, b_phi,
                                                b_g, th, ph, vt);
  attn_core_kernel<<<dim3(16, 16), 512, 0, stream>>>(th, ph, vt, Og);
  outconv_kernel<<<dim3(32, 16), 512, 0, stream>>>(Og, wo, b_out, gamma, x, out);
}